// Round 1
// baseline (27623.398 us; speedup 1.0000x reference)
//
#include <hip/hip_runtime.h>

// Problem constants (B=32, C=128, H=72, W=200, K=9, PAD=4)
#define CC  128
#define HH  72
#define WW  200
#define HW_ (HH*WW)        // 14400
#define CHW (CC*HW_)       // 1843200

// ---------------------------------------------------------------------------
// stepW: one step of the D or U sweep (conv along W, recurrence along H).
//   out[b][c][h_dst][l] += relu(bias[c] + sum_{ci,k} w[c][ci][k]*out[b][ci][h_src][l+k-4])
// Grid: (4 l-tiles of 64, 2 c-tiles of 64, 32 b). Block: 256 threads.
// Thread = (lgrp = t&15 -> 4 consecutive l, cgrp = t>>4 -> 4 consecutive c_out).
// LDS: prev row window [lbase-4, lbase+68) for all 128 ci  (128*72 fl = 36 KB).
// ---------------------------------------------------------------------------
__global__ __launch_bounds__(256) void stepW_kern(
    float* __restrict__ out, const float* __restrict__ wgt,
    const float* __restrict__ bias, int h_src, int h_dst)
{
    __shared__ float lds[CC * 72];
    const int b     = blockIdx.z;
    const int lbase = blockIdx.x * 64;
    const int cbase = blockIdx.y * 64;
    const int t     = threadIdx.x;

    const float* src = out + (size_t)b * CHW + (size_t)h_src * WW;
    for (int i = t; i < CC * 72; i += 256) {
        int ci = i / 72;
        int lo = i - ci * 72;
        int l  = lbase - 4 + lo;
        lds[i] = (l >= 0 && l < WW) ? src[(size_t)ci * HW_ + l] : 0.f;
    }
    __syncthreads();

    const int lgrp = t & 15;
    const int cgrp = t >> 4;
    const int l0   = lbase + lgrp * 4;
    const int c0   = cbase + cgrp * 4;

    float acc[4][4] = {};
    for (int ci = 0; ci < CC; ci++) {
        float p[12];
        const float* lp = &lds[ci * 72 + lgrp * 4];
        #pragma unroll
        for (int j = 0; j < 12; j++) p[j] = lp[j];
        #pragma unroll
        for (int c = 0; c < 4; c++) {
            const float* wp = wgt + ((size_t)(c0 + c) * CC + ci) * 9;
            #pragma unroll
            for (int k = 0; k < 9; k++) {
                const float wv = wp[k];
                #pragma unroll
                for (int j = 0; j < 4; j++)
                    acc[c][j] = fmaf(wv, p[j + k], acc[c][j]);
            }
        }
    }

    if (l0 < WW) {   // tail tile: l0 in {192,196} valid, others skipped (W%4==0)
        #pragma unroll
        for (int c = 0; c < 4; c++) {
            float* po = out + (size_t)b * CHW + (size_t)(c0 + c) * HW_
                            + (size_t)h_dst * WW + l0;
            float4 v = *(float4*)po;
            const float bb = bias[c0 + c];
            v.x += fmaxf(acc[c][0] + bb, 0.f);
            v.y += fmaxf(acc[c][1] + bb, 0.f);
            v.z += fmaxf(acc[c][2] + bb, 0.f);
            v.w += fmaxf(acc[c][3] + bb, 0.f);
            *(float4*)po = v;
        }
    }
}

// ---------------------------------------------------------------------------
// stepH: one step of the R or L sweep (conv along H, recurrence along W).
//   out[b][c][h][w_dst] += relu(bias[c] + sum_{ci,k} w[c][ci][k]*out[b][ci][h+k-4][w_src])
// Grid: (3 h-tiles of 24, 4 c-tiles of 32, 32 b). Block: 256 threads.
// Thread = (hgrp = t&7 -> 3 consecutive h, cgrp = t>>3 -> 1 c_out).
// LDS: prev column window [hbase-4, hbase+28) for all ci (128*32 fl = 16 KB).
// ---------------------------------------------------------------------------
__global__ __launch_bounds__(256) void stepH_kern(
    float* __restrict__ out, const float* __restrict__ wgt,
    const float* __restrict__ bias, int w_src, int w_dst)
{
    __shared__ float lds[CC * 32];
    const int b     = blockIdx.z;
    const int hbase = blockIdx.x * 24;
    const int cbase = blockIdx.y * 32;
    const int t     = threadIdx.x;

    const float* srcb = out + (size_t)b * CHW + w_src;
    for (int i = t; i < CC * 32; i += 256) {
        int ci = i >> 5;
        int ho = i & 31;
        int h  = hbase - 4 + ho;
        lds[i] = (h >= 0 && h < HH) ? srcb[(size_t)ci * HW_ + (size_t)h * WW] : 0.f;
    }
    __syncthreads();

    const int hgrp  = t & 7;
    const int cgrp  = t >> 3;
    const int h0    = hgrp * 3;
    const int c_out = cbase + cgrp;

    float acc[3] = {};
    for (int ci = 0; ci < CC; ci++) {
        float p[11];
        const float* lp = &lds[ci * 32 + h0];
        #pragma unroll
        for (int j = 0; j < 11; j++) p[j] = lp[j];
        const float* wp = wgt + ((size_t)c_out * CC + ci) * 9;
        #pragma unroll
        for (int k = 0; k < 9; k++) {
            const float wv = wp[k];
            #pragma unroll
            for (int m = 0; m < 3; m++)
                acc[m] = fmaf(wv, p[m + k], acc[m]);
        }
    }

    const float bb = bias[c_out];
    float* po = out + (size_t)b * CHW + (size_t)c_out * HW_
                    + (size_t)(hbase + h0) * WW + w_dst;
    #pragma unroll
    for (int m = 0; m < 3; m++)
        po[(size_t)m * WW] += fmaxf(acc[m] + bb, 0.f);
}

// ---------------------------------------------------------------------------
extern "C" void kernel_launch(void* const* d_in, const int* in_sizes, int n_in,
                              void* d_out, int out_size, void* d_ws, size_t ws_size,
                              hipStream_t stream)
{
    const float* x   = (const float*)d_in[0];
    const float* w_d = (const float*)d_in[1];
    const float* b_d = (const float*)d_in[2];
    const float* w_u = (const float*)d_in[3];
    const float* b_u = (const float*)d_in[4];
    const float* w_r = (const float*)d_in[5];
    const float* b_r = (const float*)d_in[6];
    const float* w_l = (const float*)d_in[7];
    const float* b_l = (const float*)d_in[8];
    float* out = (float*)d_out;

    const size_t bytes = (size_t)32 * CHW * sizeof(float);
    hipMemcpyAsync(out, x, bytes, hipMemcpyDeviceToDevice, stream);

    const dim3 gA(4, 2, 32), bA(256);
    // Down sweep: h = 1..H-1, prev = h-1
    for (int h = 1; h < HH; h++)
        stepW_kern<<<gA, bA, 0, stream>>>(out, w_d, b_d, h - 1, h);
    // Up sweep: h = H-2..0, prev = h+1
    for (int h = HH - 2; h >= 0; h--)
        stepW_kern<<<gA, bA, 0, stream>>>(out, w_u, b_u, h + 1, h);

    const dim3 gB(3, 4, 32), bB(256);
    // Right sweep: w = 1..W-1, prev = w-1
    for (int w = 1; w < WW; w++)
        stepH_kern<<<gB, bB, 0, stream>>>(out, w_r, b_r, w - 1, w);
    // Left sweep: w = W-2..0, prev = w+1
    for (int w = WW - 2; w >= 0; w--)
        stepH_kern<<<gB, bB, 0, stream>>>(out, w_l, b_l, w + 1, w);
}

// Round 2
// 20607.199 us; speedup vs baseline: 1.3405x; 1.3405x over previous
//
#include <hip/hip_runtime.h>

// Problem constants (B=32, C=128, H=72, W=200, K=9, PAD=4)
#define CC  128
#define HH  72
#define WW  200
#define HW_ (HH*WW)        // 14400
#define CHW (CC*HW_)       // 1843200

// ---------------------------------------------------------------------------
// Generic sweep step on a (B, C, R, L) state where L is the contiguous axis
// and the recurrence walks R:
//   st[b][c][r_dst][l] += relu(bias[c] + sum_{ci,k} w[c][ci][k]*st[b][ci][r_src][l+k-4])
// Grid: (ceil(L/32) l-tiles, 2 c-tiles of 64, 32 b). Block: 256 threads.
// Thread = (lgrp = t&7 -> 4 consecutive l, cgrp = t>>3 -> 2 consecutive c_out).
// LDS: prev row window [lbase-4, lbase+36) for all 128 ci (128*40 fl = 20 KB).
// LDS reads: same-address broadcast within each lgrp group; 8 lgrp * 4 banks
// = all 32 banks -> conflict-free ds_read_b128.
// ---------------------------------------------------------------------------
template<int L>
__global__ __launch_bounds__(256) void step_kern(
    float* __restrict__ st, const float* __restrict__ wgt,
    const float* __restrict__ bias, int r_src, int r_dst)
{
    __shared__ float lds[CC * 40];
    const int b     = blockIdx.z;
    const int lbase = blockIdx.x * 32;
    const int cbase = blockIdx.y * 64;
    const int t     = threadIdx.x;

    const float* src = st + (size_t)b * CHW + (size_t)r_src * L;
    #pragma unroll
    for (int i = 0; i < 20; i++) {          // 5120 elements / 256 threads
        int idx = t + i * 256;
        int ci  = idx / 40;
        int lo  = idx - ci * 40;
        int l   = lbase - 4 + lo;
        lds[idx] = (l >= 0 && l < L) ? src[(size_t)ci * HW_ + l] : 0.f;
    }
    __syncthreads();

    const int lgrp = t & 7;
    const int cgrp = t >> 3;
    const int l0   = lbase + lgrp * 4;
    const int c0   = cbase + cgrp * 2;

    float acc[2][4] = {};
    for (int ci = 0; ci < CC; ci++) {
        float p[12];
        const float* lp = &lds[ci * 40 + lgrp * 4];
        #pragma unroll
        for (int j = 0; j < 12; j++) p[j] = lp[j];
        #pragma unroll
        for (int c = 0; c < 2; c++) {
            const float* wp = wgt + ((size_t)(c0 + c) * CC + ci) * 9;
            #pragma unroll
            for (int k = 0; k < 9; k++) {
                const float wv = wp[k];
                #pragma unroll
                for (int j = 0; j < 4; j++)
                    acc[c][j] = fmaf(wv, p[j + k], acc[c][j]);
            }
        }
    }

    if (l0 < L) {   // tail tiles: L%4==0 so no partial float4
        #pragma unroll
        for (int c = 0; c < 2; c++) {
            float* po = st + (size_t)b * CHW + (size_t)(c0 + c) * HW_
                           + (size_t)r_dst * L + l0;
            float4 v = *(float4*)po;
            const float bb = bias[c0 + c];
            v.x += fmaxf(acc[c][0] + bb, 0.f);
            v.y += fmaxf(acc[c][1] + bb, 0.f);
            v.z += fmaxf(acc[c][2] + bb, 0.f);
            v.w += fmaxf(acc[c][3] + bb, 0.f);
            *(float4*)po = v;
        }
    }
}

// ---------------------------------------------------------------------------
// Per-plane 2D transpose: in (rows x cols) -> out (cols x rows), z = B*C planes.
// Block 32x8, LDS 32x33 to break bank conflicts.
// ---------------------------------------------------------------------------
__global__ __launch_bounds__(256) void transpose_kern(
    const float* __restrict__ in, float* __restrict__ outp, int rows, int cols)
{
    __shared__ float tile[32][33];
    const size_t plane = (size_t)rows * cols;
    const float* ip = in   + (size_t)blockIdx.z * plane;
    float*       op = outp + (size_t)blockIdx.z * plane;
    const int c0 = blockIdx.x * 32, r0 = blockIdx.y * 32;
    const int tx = threadIdx.x, ty = threadIdx.y;

    #pragma unroll
    for (int i = 0; i < 32; i += 8) {
        int r = r0 + ty + i, c = c0 + tx;
        if (r < rows && c < cols) tile[ty + i][tx] = ip[(size_t)r * cols + c];
    }
    __syncthreads();
    #pragma unroll
    for (int i = 0; i < 32; i += 8) {
        int r = c0 + ty + i, c = r0 + tx;
        if (r < cols && c < rows) op[(size_t)r * rows + c] = tile[tx][ty + i];
    }
}

// ---------------------------------------------------------------------------
// Fallback (round-1) column-step kernel, used only if ws_size is too small
// for the transposed workspace.
// ---------------------------------------------------------------------------
__global__ __launch_bounds__(256) void stepH_kern(
    float* __restrict__ out, const float* __restrict__ wgt,
    const float* __restrict__ bias, int w_src, int w_dst)
{
    __shared__ float lds[CC * 32];
    const int b     = blockIdx.z;
    const int hbase = blockIdx.x * 24;
    const int cbase = blockIdx.y * 32;
    const int t     = threadIdx.x;

    const float* srcb = out + (size_t)b * CHW + w_src;
    for (int i = t; i < CC * 32; i += 256) {
        int ci = i >> 5;
        int ho = i & 31;
        int h  = hbase - 4 + ho;
        lds[i] = (h >= 0 && h < HH) ? srcb[(size_t)ci * HW_ + (size_t)h * WW] : 0.f;
    }
    __syncthreads();

    const int hgrp  = t & 7;
    const int cgrp  = t >> 3;
    const int h0    = hgrp * 3;
    const int c_out = cbase + cgrp;

    float acc[3] = {};
    for (int ci = 0; ci < CC; ci++) {
        float p[11];
        const float* lp = &lds[ci * 32 + h0];
        #pragma unroll
        for (int j = 0; j < 11; j++) p[j] = lp[j];
        const float* wp = wgt + ((size_t)c_out * CC + ci) * 9;
        #pragma unroll
        for (int k = 0; k < 9; k++) {
            const float wv = wp[k];
            #pragma unroll
            for (int m = 0; m < 3; m++)
                acc[m] = fmaf(wv, p[m + k], acc[m]);
        }
    }

    const float bb = bias[c_out];
    float* po = out + (size_t)b * CHW + (size_t)c_out * HW_
                    + (size_t)(hbase + h0) * WW + w_dst;
    #pragma unroll
    for (int m = 0; m < 3; m++)
        po[(size_t)m * WW] += fmaxf(acc[m] + bb, 0.f);
}

// ---------------------------------------------------------------------------
extern "C" void kernel_launch(void* const* d_in, const int* in_sizes, int n_in,
                              void* d_out, int out_size, void* d_ws, size_t ws_size,
                              hipStream_t stream)
{
    const float* x   = (const float*)d_in[0];
    const float* w_d = (const float*)d_in[1];
    const float* b_d = (const float*)d_in[2];
    const float* w_u = (const float*)d_in[3];
    const float* b_u = (const float*)d_in[4];
    const float* w_r = (const float*)d_in[5];
    const float* b_r = (const float*)d_in[6];
    const float* w_l = (const float*)d_in[7];
    const float* b_l = (const float*)d_in[8];
    float* out = (float*)d_out;
    float* ws  = (float*)d_ws;

    const size_t bytes = (size_t)32 * CHW * sizeof(float);
    hipMemcpyAsync(out, x, bytes, hipMemcpyDeviceToDevice, stream);

    // --- D/U sweeps: conv along W (contiguous), recurrence along H ---
    const dim3 gW(7, 2, 32), blk(256);
    for (int h = 1; h < HH; h++)
        step_kern<WW><<<gW, blk, 0, stream>>>(out, w_d, b_d, h - 1, h);
    for (int h = HH - 2; h >= 0; h--)
        step_kern<WW><<<gW, blk, 0, stream>>>(out, w_u, b_u, h + 1, h);

    if (ws_size >= bytes) {
        // --- Transpose to (B, C, W, H): conv axis H becomes contiguous ---
        transpose_kern<<<dim3(7, 3, 4096), dim3(32, 8), 0, stream>>>(out, ws, HH, WW);

        const dim3 gH(3, 2, 32);
        for (int w = 1; w < WW; w++)
            step_kern<HH><<<gH, blk, 0, stream>>>(ws, w_r, b_r, w - 1, w);
        for (int w = WW - 2; w >= 0; w--)
            step_kern<HH><<<gH, blk, 0, stream>>>(ws, w_l, b_l, w + 1, w);

        transpose_kern<<<dim3(3, 7, 4096), dim3(32, 8), 0, stream>>>(ws, out, WW, HH);
    } else {
        // Fallback: strided column kernel (round-1 path, correct but slow)
        const dim3 gB(3, 4, 32);
        for (int w = 1; w < WW; w++)
            stepH_kern<<<gB, blk, 0, stream>>>(out, w_r, b_r, w - 1, w);
        for (int w = WW - 2; w >= 0; w--)
            stepH_kern<<<gB, blk, 0, stream>>>(out, w_l, b_l, w + 1, w);
    }
}